// Round 3
// baseline (831.403 us; speedup 1.0000x reference)
//
#include <hip/hip_runtime.h>
#include <hip/hip_bf16.h>

// ---------------- problem constants ----------------
#define NB   256        // batch
#define NT   205        // tokens per batch (1 CLS + 196 patches + 8 concept)
#define DIMD 768
#define NCC  8
#define NPP  196
#define LDQ  2304       // qkv row stride (Q|K|V concatenated)
#define SCL  0.03608439182435161f   // 768^-0.5

using u16 = unsigned short;
using u32 = unsigned int;
using bf16x8 = __attribute__((ext_vector_type(8))) short;
using f32x4  = __attribute__((ext_vector_type(4))) float;

// ---------------- buffer byte offsets ----------------
// d_ws:  wb[2304x768 bf16] | qkv[52480x2304 bf16]   (max 245,366,784 B, evidenced safe)
#define WS_WB   0ul
#define WS_QKV  3538944ul
// d_out: [0,43033600) = attn fp32 (final, written by k_scores/k_mask/k_softmax).
//        [43033600, 204129280) = out fp32 (final, written directly by k_pv).
//        Before k_pv, that tail holds temporaries (all dead by k_pv time):
//          xb (bf16 x, dead after k_qkv)            @ +43033600
//          qc, z, reg (fp32 side-path, dead after k_mask) @ +143696896
#define DO_OUT  43033600ul
#define DO_XB   43033600ul
#define DO_QC   143696896ul
#define DO_Z    149988352ul
#define DO_REG  156279808ul

__device__ __forceinline__ u16 f2bf(float f) {
  u32 u = __float_as_uint(f);
  u += 0x7FFFu + ((u >> 16) & 1u);
  return (u16)(u >> 16);
}

__device__ __forceinline__ void gld16(const void* g, void* l) {
  __builtin_amdgcn_global_load_lds((const __attribute__((address_space(1))) u32*)g,
                                   (__attribute__((address_space(3))) u32*)l, 16, 0, 0);
}

__device__ __forceinline__ f32x4 mfma16(bf16x8 a, bf16x8 b, f32x4 c) {
  return __builtin_amdgcn_mfma_f32_16x16x32_bf16(a, b, c, 0, 0, 0);
}

// ---------------- fp32 -> bf16 cast, 8 elems/thread ----------------
__global__ __launch_bounds__(256) void k_cast(const float* __restrict__ s, u16* __restrict__ d, int n8) {
  int i = blockIdx.x * 256 + threadIdx.x;
  if (i >= n8) return;
  const float4* s4 = (const float4*)s;
  float4 a = s4[2*(size_t)i], b = s4[2*(size_t)i + 1];
  union { u16 h[8]; uint4 v; } r;
  r.h[0]=f2bf(a.x); r.h[1]=f2bf(a.y); r.h[2]=f2bf(a.z); r.h[3]=f2bf(a.w);
  r.h[4]=f2bf(b.x); r.h[5]=f2bf(b.y); r.h[6]=f2bf(b.z); r.h[7]=f2bf(b.w);
  *(uint4*)(d + 8*(size_t)i) = r.v;
}

// ---------------- big QKV GEMM: C[52480,2304] = A[52480,768] * Bt[2304,768]^T (bf16) ----------------
__global__ __launch_bounds__(256) void k_qkv(const u16* __restrict__ A, const u16* __restrict__ Bt, u16* __restrict__ C) {
  __shared__ u16 As[128*32];
  __shared__ u16 Bs[128*32];
  const int tid = threadIdx.x, wid = tid >> 6, lane = tid & 63;
  const int bm = blockIdx.x / 18, bn = blockIdx.x % 18;
  const size_t m0 = (size_t)bm * 128;
  const int n0 = bn * 128;
  const int wr = (wid >> 1) * 64, wc = (wid & 1) * 64;
  const int fr = lane & 15, fg = lane >> 4;
  const int eb0 = (wid*2+0)*512, eb1 = (wid*2+1)*512;
  const int e0 = eb0 + lane*8, e1 = eb1 + lane*8;
  const int r0 = e0 >> 5, c0 = e0 & 31, r1 = e1 >> 5, c1 = e1 & 31;
  f32x4 acc[4][4] = {};
  for (int k0 = 0; k0 < 768; k0 += 32) {
    gld16(A + (m0 + r0)*768 + k0 + c0, (char*)As + 2*eb0);
    gld16(A + (m0 + r1)*768 + k0 + c1, (char*)As + 2*eb1);
    gld16(Bt + (size_t)(n0 + r0)*768 + k0 + c0, (char*)Bs + 2*eb0);
    gld16(Bt + (size_t)(n0 + r1)*768 + k0 + c1, (char*)Bs + 2*eb1);
    __syncthreads();
    bf16x8 av[4], bv[4];
    #pragma unroll
    for (int m = 0; m < 4; ++m) av[m] = *(const bf16x8*)&As[(wr + m*16 + fr)*32 + fg*8];
    #pragma unroll
    for (int n = 0; n < 4; ++n) bv[n] = *(const bf16x8*)&Bs[(wc + n*16 + fr)*32 + fg*8];
    #pragma unroll
    for (int m = 0; m < 4; ++m)
      #pragma unroll
      for (int n = 0; n < 4; ++n)
        acc[m][n] = mfma16(av[m], bv[n], acc[m][n]);
    __syncthreads();
  }
  #pragma unroll
  for (int m = 0; m < 4; ++m) {
    #pragma unroll
    for (int j = 0; j < 4; ++j) {
      size_t row = m0 + wr + m*16 + fg*4 + j;
      u16* cp = C + row*LDQ + n0 + wc;
      #pragma unroll
      for (int n = 0; n < 4; ++n) cp[n*16 + fr] = f2bf(acc[m][n][j]);
    }
  }
}

// ---------------- fp32 tiled GEMM (64x64 tile, 4x4/thread) ----------------
template<bool BT, bool GATHER>
__global__ __launch_bounds__(256) void k_gemm32(const float* __restrict__ A, const float* __restrict__ Bm,
                                                float* __restrict__ C, int lda, int ldb, int ldc,
                                                int K, int nbn) {
  __shared__ float As[16][68];
  __shared__ float Bs[16][68];
  const int tid = threadIdx.x;
  const int m0 = (blockIdx.x / nbn) * 64, n0 = (blockIdx.x % nbn) * 64;
  const int ty = tid >> 4, tx = tid & 15;
  const int sr = tid >> 2, sk = (tid & 3) * 4;
  float acc[4][4] = {};
  for (int k0 = 0; k0 < K; k0 += 16) {
    size_t arow = (size_t)(m0 + sr);
    if (GATHER) arow = (arow >> 3) * 205 + 197 + (arow & 7);
    float4 av = *(const float4*)&A[arow * lda + k0 + sk];
    As[sk+0][sr] = av.x; As[sk+1][sr] = av.y; As[sk+2][sr] = av.z; As[sk+3][sr] = av.w;
    if (BT) {
      float4 bv = *(const float4*)&Bm[(size_t)(n0 + sr) * ldb + k0 + sk];
      Bs[sk+0][sr] = bv.x; Bs[sk+1][sr] = bv.y; Bs[sk+2][sr] = bv.z; Bs[sk+3][sr] = bv.w;
    } else {
      const int bk = tid >> 4, bn4 = (tid & 15) * 4;
      float4 bv = *(const float4*)&Bm[(size_t)(k0 + bk) * ldb + n0 + bn4];
      *(float4*)&Bs[bk][bn4] = bv;
    }
    __syncthreads();
    #pragma unroll
    for (int kk = 0; kk < 16; ++kk) {
      float4 a4 = *(const float4*)&As[kk][ty*4];
      float4 b4 = *(const float4*)&Bs[kk][tx*4];
      float a[4] = {a4.x, a4.y, a4.z, a4.w};
      float b[4] = {b4.x, b4.y, b4.z, b4.w};
      #pragma unroll
      for (int i = 0; i < 4; ++i)
        #pragma unroll
        for (int j = 0; j < 4; ++j) acc[i][j] += a[i]*b[j];
    }
    __syncthreads();
  }
  #pragma unroll
  for (int i = 0; i < 4; ++i) {
    float4 o = {acc[i][0], acc[i][1], acc[i][2], acc[i][3]};
    *(float4*)&C[(size_t)(m0 + ty*4 + i) * ldc + n0 + tx*4] = o;
  }
}

// ---------------- region scores: reg[r,p] = z[r,:] . x[b, 1+p, :]  (fp32 exact path) ----------------
__global__ __launch_bounds__(256) void k_region(const float* __restrict__ z, const float* __restrict__ x,
                                                float* __restrict__ reg) {
  const int r = blockIdx.x, b = r >> 3;
  __shared__ float zs[768];
  for (int i = threadIdx.x; i < 768; i += 256) zs[i] = z[(size_t)r*768 + i];
  __syncthreads();
  const int p = threadIdx.x;
  if (p >= NPP) return;
  const float* xp = x + ((size_t)b*NT + 1 + p) * DIMD;
  float acc = 0.f;
  #pragma unroll 8
  for (int d = 0; d < 768; d += 4) {
    float4 xv = *(const float4*)&xp[d];
    acc += zs[d]*xv.x + zs[d+1]*xv.y + zs[d+2]*xv.z + zs[d+3]*xv.w;
  }
  reg[(size_t)r*NPP + p] = acc;
}

// ---------------- batched scores: S[b] = Q_b K_b^T (bf16 MFMA, fp32 out) ----------------
__global__ __launch_bounds__(256) void k_scores(const u16* __restrict__ qkv, float* __restrict__ S) {
  __shared__ u16 Qs[64*40];
  __shared__ u16 Ks[64*40];
  const int tid = threadIdx.x, wid = tid >> 6, lane = tid & 63;
  const int b = blockIdx.x >> 4, tile = blockIdx.x & 15;
  const int i0 = (tile >> 2) * 64, j0 = (tile & 3) * 64;
  const size_t base = (size_t)b * NT * LDQ;
  const int wr = (wid >> 1) * 32, wc = (wid & 1) * 32;
  const int fr = lane & 15, fg = lane >> 4;
  const int sr = tid >> 2, sc = (tid & 3) * 8;
  const int tq = min(i0 + sr, NT-1), tk = min(j0 + sr, NT-1);
  const u16* gq = qkv + base + (size_t)tq * LDQ + sc;
  const u16* gk = qkv + base + (size_t)tk * LDQ + 768 + sc;
  f32x4 acc[2][2] = {};
  for (int k0 = 0; k0 < 768; k0 += 32) {
    bf16x8 qa = *(const bf16x8*)(gq + k0);
    bf16x8 ka = *(const bf16x8*)(gk + k0);
    *(bf16x8*)&Qs[sr*40 + sc] = qa;
    *(bf16x8*)&Ks[sr*40 + sc] = ka;
    __syncthreads();
    bf16x8 av[2], bv[2];
    av[0] = *(const bf16x8*)&Qs[(wr      + fr)*40 + fg*8];
    av[1] = *(const bf16x8*)&Qs[(wr + 16 + fr)*40 + fg*8];
    bv[0] = *(const bf16x8*)&Ks[(wc      + fr)*40 + fg*8];
    bv[1] = *(const bf16x8*)&Ks[(wc + 16 + fr)*40 + fg*8];
    acc[0][0] = mfma16(av[0], bv[0], acc[0][0]);
    acc[0][1] = mfma16(av[0], bv[1], acc[0][1]);
    acc[1][0] = mfma16(av[1], bv[0], acc[1][0]);
    acc[1][1] = mfma16(av[1], bv[1], acc[1][1]);
    __syncthreads();
  }
  #pragma unroll
  for (int m = 0; m < 2; ++m)
    #pragma unroll
    for (int n = 0; n < 2; ++n)
      #pragma unroll
      for (int j = 0; j < 4; ++j) {
        int i  = i0 + wr + m*16 + fg*4 + j;
        int jj = j0 + wc + n*16 + fr;
        if (i < NT && jj < NT)
          S[(size_t)b*NT*NT + (size_t)i*NT + jj] = acc[m][n][j];
      }
}

// ---------------- argmax + gaussian mask, overwrite concept-row region in S (fp32 exact) ----------------
__global__ __launch_bounds__(64) void k_mask(const float* __restrict__ reg, float* __restrict__ S) {
  const int r = blockIdx.x, b = r >> 3, c = r & 7;
  const int lane = threadIdx.x;
  float best = -1e30f; int bi = 0;
  #pragma unroll
  for (int q = 0; q < 4; ++q) {
    int p = lane + q*64;
    if (p < NPP) {
      float v = reg[(size_t)r*NPP + p];
      if (v > best) { best = v; bi = p; }
    }
  }
  for (int off = 32; off; off >>= 1) {
    float ov = __shfl_xor(best, off);
    int   oi = __shfl_xor(bi, off);
    if (ov > best || (ov == best && oi < bi)) { best = ov; bi = oi; }
  }
  // faithful to reference: center is (h = loc%14, w = loc//14)  [transposed meshgrid]
  const float mx = (float)(bi % 14), my = (float)(bi / 14);
  float* Sr = S + ((size_t)b*NT + 197 + c) * NT + 1;
  #pragma unroll
  for (int q = 0; q < 4; ++q) {
    int p = lane + q*64;
    if (p < NPP) {
      float h = (float)(p / 14), w = (float)(p % 14);
      float d2 = (h - mx)*(h - mx) + (w - my)*(w - my);
      Sr[p] = reg[(size_t)r*NPP + p] * __expf(-2.0f * d2);   // 1/(2*sigma^2)=2, g_max=1
    }
  }
}

// ---------------- softmax per row: fp32 in-place (S becomes final attn probs) ----------------
__global__ __launch_bounds__(256) void k_softmax(float* __restrict__ S) {
  const int row = blockIdx.x * 4 + (threadIdx.x >> 6);
  const int lane = threadIdx.x & 63;
  float* sr = S + (size_t)row * NT;
  float v[4];
  #pragma unroll
  for (int q = 0; q < 4; ++q) {
    int p = lane + q*64;
    v[q] = (p < NT) ? sr[p] * SCL : -1e30f;
  }
  float m = fmaxf(fmaxf(v[0], v[1]), fmaxf(v[2], v[3]));
  for (int off = 32; off; off >>= 1) m = fmaxf(m, __shfl_xor(m, off));
  float e[4], s = 0.f;
  #pragma unroll
  for (int q = 0; q < 4; ++q) {
    int p = lane + q*64;
    e[q] = (p < NT) ? __expf(v[q] - m) : 0.f;
    s += e[q];
  }
  for (int off = 32; off; off >>= 1) s += __shfl_xor(s, off);
  const float inv = 1.0f / s;
  #pragma unroll
  for (int q = 0; q < 4; ++q) {
    int p = lane + q*64;
    if (p < NT) sr[p] = e[q] * inv;
  }
}

// ---------------- batched PV: out[b] = P_b V_b, direct from S (fp32) and qkv (V part) ----------------
// P staged as bf16 from fp32 probs; V staged untransposed [k][e]; B-fragment built by
// definition via scalar LDS reads: lane l, reg j  <-  V[k0 + (l>>4)*8 + j][e0 + wc + n*16 + (l&15)].
__global__ __launch_bounds__(256) void k_pv(const float* __restrict__ S, const u16* __restrict__ qkv,
                                            float* __restrict__ out) {
  __shared__ u16 Ps[64*40];   // [i-row][k]   (k-pad 40)
  __shared__ u16 Vs[32*72];   // [k-row][e]   (e-pad 72)
  const int tid = threadIdx.x, wid = tid >> 6, lane = tid & 63;
  const int b = blockIdx.x / 48, t = blockIdx.x % 48;
  const int i0 = (t / 12) * 64, e0 = (t % 12) * 64;
  const int wr = (wid >> 1) * 32, wc = (wid & 1) * 32;
  const int fr = lane & 15, fg = lane >> 4;
  const int sr = tid >> 2, sc = (tid & 3) * 8;   // P staging: 64 rows x 32 k
  const int vr = tid >> 3, ve = (tid & 7) * 8;   // V staging: 32 k x 64 e
  const int ip = min(i0 + sr, NT-1);
  const float* Sp = S + ((size_t)b*NT + ip) * NT;
  f32x4 acc[2][2] = {};
  for (int k0 = 0; k0 < 224; k0 += 32) {
    // stage P (fp32 -> bf16), zero-pad k >= 205
    union { u16 h[8]; uint4 v; } pr_;
    #pragma unroll
    for (int j = 0; j < 8; ++j) {
      int k = k0 + sc + j;
      pr_.h[j] = (k < NT) ? f2bf(Sp[k]) : (u16)0;
    }
    *(uint4*)&Ps[sr*40 + sc] = pr_.v;
    // stage V rows k0+vr (clamped; garbage rows killed by P=0 pad)
    const int kv = min(k0 + vr, NT-1);
    bf16x8 vv = *(const bf16x8*)&qkv[((size_t)b*NT + kv)*LDQ + 1536 + e0 + ve];
    *(bf16x8*)&Vs[vr*72 + ve] = vv;
    __syncthreads();
    bf16x8 av[2], bv[2];
    av[0] = *(const bf16x8*)&Ps[(wr      + fr)*40 + fg*8];
    av[1] = *(const bf16x8*)&Ps[(wr + 16 + fr)*40 + fg*8];
    #pragma unroll
    for (int n = 0; n < 2; ++n)
      #pragma unroll
      for (int j = 0; j < 8; ++j)
        bv[n][j] = (short)Vs[(fg*8 + j)*72 + wc + n*16 + fr];
    acc[0][0] = mfma16(av[0], bv[0], acc[0][0]);
    acc[0][1] = mfma16(av[0], bv[1], acc[0][1]);
    acc[1][0] = mfma16(av[1], bv[0], acc[1][0]);
    acc[1][1] = mfma16(av[1], bv[1], acc[1][1]);
    __syncthreads();
  }
  #pragma unroll
  for (int m = 0; m < 2; ++m)
    #pragma unroll
    for (int n = 0; n < 2; ++n)
      #pragma unroll
      for (int j = 0; j < 4; ++j) {
        int i = i0 + wr + m*16 + fg*4 + j;
        int e = e0 + wc + n*16 + fr;
        if (i < NT)
          out[((size_t)b*NT + i)*DIMD + e] = acc[m][n][j];
      }
}

extern "C" void kernel_launch(void* const* d_in, const int* in_sizes, int n_in,
                              void* d_out, int out_size, void* d_ws, size_t ws_size,
                              hipStream_t stream) {
  const float* x  = (const float*)d_in[0];
  const float* Wq = (const float*)d_in[1];
  const float* Wk = (const float*)d_in[2];
  const float* Wv = (const float*)d_in[3];
  char* ws = (char*)d_ws;
  char* ob = (char*)d_out;

  u16*   wb   = (u16*)(ws + WS_WB);     // [2304][768] bf16: Wq|Wk|Wv
  u16*   qkv  = (u16*)(ws + WS_QKV);    // [52480][2304] bf16 (live until k_pv done)

  float* S    = (float*)ob;             // [256][205][205] scores -> final attn probs
  float* outp = (float*)(ob + DO_OUT);  // [256][205][768] final output (direct)
  u16*   xb   = (u16*)(ob + DO_XB);     // bf16 x (temp, dead after k_qkv)
  float* qc   = (float*)(ob + DO_QC);   // [2048][768] fp32 concept queries
  float* zz   = (float*)(ob + DO_Z);    // [2048][768] fp32 qc*Wk
  float* reg  = (float*)(ob + DO_REG);  // [2048][196] fp32 region scores (dead after k_mask)

  // 1) casts to bf16
  k_cast<<<19680, 256, 0, stream>>>(x,  xb, 5038080);
  k_cast<<<288,   256, 0, stream>>>(Wq, wb,           73728);
  k_cast<<<288,   256, 0, stream>>>(Wk, wb + 589824,  73728);
  k_cast<<<288,   256, 0, stream>>>(Wv, wb + 1179648, 73728);
  // 2) fused QKV projection (bf16 MFMA)
  k_qkv<<<7380, 256, 0, stream>>>(xb, wb, qkv);
  // 3) exact fp32 path for argmax region: qc = Xc*Wq^T ; z = qc*Wk ; reg = z*Xp^T
  k_gemm32<true,  true ><<<384, 256, 0, stream>>>(x,  Wq, qc, 768, 768, 768, 768, 12);
  k_gemm32<false, false><<<384, 256, 0, stream>>>(qc, Wk, zz, 768, 768, 768, 768, 12);
  k_region<<<2048, 256, 0, stream>>>(zz, x, reg);
  // 4) full attention scores (bf16 MFMA, fp32 into d_out)
  k_scores<<<4096, 256, 0, stream>>>(qkv, S);
  // 5) argmax + gaussian mask overwrite (fp32 exact)
  k_mask<<<2048, 64, 0, stream>>>(reg, S);
  // 6) softmax in place (S becomes the final attn output)
  k_softmax<<<13120, 256, 0, stream>>>(S);
  // 7) PV directly from S (fp32 probs) + qkv V-part, writing final out region
  k_pv<<<12288, 256, 0, stream>>>(S, qkv, outp);
}

// Round 4
// 830.559 us; speedup vs baseline: 1.0010x; 1.0010x over previous
//
#include <hip/hip_runtime.h>
#include <hip/hip_bf16.h>

// ---------------- problem constants ----------------
#define NB   256        // batch
#define NT   205        // tokens per batch (1 CLS + 196 patches + 8 concept)
#define DIMD 768
#define NCC  8
#define NPP  196
#define LDQ  2304       // qkv row stride (Q|K|V concatenated)
#define SCL  0.03608439182435161f   // 768^-0.5

using u16 = unsigned short;
using u32 = unsigned int;
using bf16x8 = __attribute__((ext_vector_type(8))) short;
using f32x4  = __attribute__((ext_vector_type(4))) float;

// ---------------- buffer byte offsets ----------------
// d_ws:  wb[2304x768 bf16] | qkv[52480x2304 bf16]   (max 245,366,784 B, evidenced safe)
#define WS_WB   0ul
#define WS_QKV  3538944ul
// d_out: [0,43033600) = attn fp32 (final). [43033600,204129280) = out fp32 (final, by k_pv).
//        Temporaries in the tail (dead before k_pv writes):
//          xb (bf16 x, dead after k_qkv)                  @ +43033600
//          Mmat = Wq^T*Wk fp32 [768x768]                  @ +143696896
//          zz fp32 [2048x768], reg fp32 [2048x196]        @ +149988352 / +156279808
#define DO_OUT  43033600ul
#define DO_XB   43033600ul
#define DO_M    143696896ul
#define DO_Z    149988352ul
#define DO_REG  156279808ul

__device__ __forceinline__ u16 f2bf(float f) {
  u32 u = __float_as_uint(f);
  u += 0x7FFFu + ((u >> 16) & 1u);
  return (u16)(u >> 16);
}

__device__ __forceinline__ void gld16(const void* g, void* l) {
  __builtin_amdgcn_global_load_lds((const __attribute__((address_space(1))) u32*)g,
                                   (__attribute__((address_space(3))) u32*)l, 16, 0, 0);
}

__device__ __forceinline__ f32x4 mfma16(bf16x8 a, bf16x8 b, f32x4 c) {
  return __builtin_amdgcn_mfma_f32_16x16x32_bf16(a, b, c, 0, 0, 0);
}

// ---------------- fp32 -> bf16 cast, 8 elems/thread ----------------
__global__ __launch_bounds__(256) void k_cast(const float* __restrict__ s, u16* __restrict__ d, int n8) {
  int i = blockIdx.x * 256 + threadIdx.x;
  if (i >= n8) return;
  const float4* s4 = (const float4*)s;
  float4 a = s4[2*(size_t)i], b = s4[2*(size_t)i + 1];
  union { u16 h[8]; uint4 v; } r;
  r.h[0]=f2bf(a.x); r.h[1]=f2bf(a.y); r.h[2]=f2bf(a.z); r.h[3]=f2bf(a.w);
  r.h[4]=f2bf(b.x); r.h[5]=f2bf(b.y); r.h[6]=f2bf(b.z); r.h[7]=f2bf(b.w);
  *(uint4*)(d + 8*(size_t)i) = r.v;
}

// ---------------- big QKV GEMM: C[52480,2304] = A[52480,768] * Bt[2304,768]^T (bf16) ----------------
__global__ __launch_bounds__(256) void k_qkv(const u16* __restrict__ A, const u16* __restrict__ Bt, u16* __restrict__ C) {
  __shared__ u16 As[128*32];
  __shared__ u16 Bs[128*32];
  const int tid = threadIdx.x, wid = tid >> 6, lane = tid & 63;
  const int bm = blockIdx.x / 18, bn = blockIdx.x % 18;
  const size_t m0 = (size_t)bm * 128;
  const int n0 = bn * 128;
  const int wr = (wid >> 1) * 64, wc = (wid & 1) * 64;
  const int fr = lane & 15, fg = lane >> 4;
  const int eb0 = (wid*2+0)*512, eb1 = (wid*2+1)*512;
  const int e0 = eb0 + lane*8, e1 = eb1 + lane*8;
  const int r0 = e0 >> 5, c0 = e0 & 31, r1 = e1 >> 5, c1 = e1 & 31;
  f32x4 acc[4][4] = {};
  for (int k0 = 0; k0 < 768; k0 += 32) {
    gld16(A + (m0 + r0)*768 + k0 + c0, (char*)As + 2*eb0);
    gld16(A + (m0 + r1)*768 + k0 + c1, (char*)As + 2*eb1);
    gld16(Bt + (size_t)(n0 + r0)*768 + k0 + c0, (char*)Bs + 2*eb0);
    gld16(Bt + (size_t)(n0 + r1)*768 + k0 + c1, (char*)Bs + 2*eb1);
    __syncthreads();
    bf16x8 av[4], bv[4];
    #pragma unroll
    for (int m = 0; m < 4; ++m) av[m] = *(const bf16x8*)&As[(wr + m*16 + fr)*32 + fg*8];
    #pragma unroll
    for (int n = 0; n < 4; ++n) bv[n] = *(const bf16x8*)&Bs[(wc + n*16 + fr)*32 + fg*8];
    #pragma unroll
    for (int m = 0; m < 4; ++m)
      #pragma unroll
      for (int n = 0; n < 4; ++n)
        acc[m][n] = mfma16(av[m], bv[n], acc[m][n]);
    __syncthreads();
  }
  #pragma unroll
  for (int m = 0; m < 4; ++m) {
    #pragma unroll
    for (int j = 0; j < 4; ++j) {
      size_t row = m0 + wr + m*16 + fg*4 + j;
      u16* cp = C + row*LDQ + n0 + wc;
      #pragma unroll
      for (int n = 0; n < 4; ++n) cp[n*16 + fr] = f2bf(acc[m][n][j]);
    }
  }
}

// ---------------- fp32 tiled GEMM (64x64 tile, 4x4/thread) ----------------
// AM: 0 = A stored [M,K]; 1 = A stored [K,M] (transposed); 2 = [M,K] with concept-row gather.
// BT: true = B stored [N,K]; false = [K,N].
template<int AM, bool BT>
__global__ __launch_bounds__(256) void k_gemm32(const float* __restrict__ A, const float* __restrict__ Bm,
                                                float* __restrict__ C, int lda, int ldb, int ldc,
                                                int K, int nbn) {
  __shared__ float As[16][68];
  __shared__ float Bs[16][68];
  const int tid = threadIdx.x;
  const int m0 = (blockIdx.x / nbn) * 64, n0 = (blockIdx.x % nbn) * 64;
  const int ty = tid >> 4, tx = tid & 15;
  const int sr = tid >> 2, sk = (tid & 3) * 4;
  float acc[4][4] = {};
  for (int k0 = 0; k0 < K; k0 += 16) {
    if (AM == 1) {
      const int ak = tid >> 4, am = (tid & 15) * 4;
      float4 av = *(const float4*)&A[(size_t)(k0 + ak) * lda + m0 + am];
      *(float4*)&As[ak][am] = av;
    } else {
      size_t arow = (size_t)(m0 + sr);
      if (AM == 2) arow = (arow >> 3) * 205 + 197 + (arow & 7);
      float4 av = *(const float4*)&A[arow * lda + k0 + sk];
      As[sk+0][sr] = av.x; As[sk+1][sr] = av.y; As[sk+2][sr] = av.z; As[sk+3][sr] = av.w;
    }
    if (BT) {
      float4 bv = *(const float4*)&Bm[(size_t)(n0 + sr) * ldb + k0 + sk];
      Bs[sk+0][sr] = bv.x; Bs[sk+1][sr] = bv.y; Bs[sk+2][sr] = bv.z; Bs[sk+3][sr] = bv.w;
    } else {
      const int bk = tid >> 4, bn4 = (tid & 15) * 4;
      float4 bv = *(const float4*)&Bm[(size_t)(k0 + bk) * ldb + n0 + bn4];
      *(float4*)&Bs[bk][bn4] = bv;
    }
    __syncthreads();
    #pragma unroll
    for (int kk = 0; kk < 16; ++kk) {
      float4 a4 = *(const float4*)&As[kk][ty*4];
      float4 b4 = *(const float4*)&Bs[kk][tx*4];
      float a[4] = {a4.x, a4.y, a4.z, a4.w};
      float b[4] = {b4.x, b4.y, b4.z, b4.w};
      #pragma unroll
      for (int i = 0; i < 4; ++i)
        #pragma unroll
        for (int j = 0; j < 4; ++j) acc[i][j] += a[i]*b[j];
    }
    __syncthreads();
  }
  #pragma unroll
  for (int i = 0; i < 4; ++i) {
    float4 o = {acc[i][0], acc[i][1], acc[i][2], acc[i][3]};
    *(float4*)&C[(size_t)(m0 + ty*4 + i) * ldc + n0 + tx*4] = o;
  }
}

// ---------------- region scores: reg[r,p] = z[r,:] . x[b, 1+p, :]  (fp32 exact path) ----------------
__global__ __launch_bounds__(256) void k_region(const float* __restrict__ z, const float* __restrict__ x,
                                                float* __restrict__ reg) {
  const int r = blockIdx.x, b = r >> 3;
  __shared__ float zs[768];
  for (int i = threadIdx.x; i < 768; i += 256) zs[i] = z[(size_t)r*768 + i];
  __syncthreads();
  const int p = threadIdx.x;
  if (p >= NPP) return;
  const float* xp = x + ((size_t)b*NT + 1 + p) * DIMD;
  float acc = 0.f;
  #pragma unroll 8
  for (int d = 0; d < 768; d += 4) {
    float4 xv = *(const float4*)&xp[d];
    acc += zs[d]*xv.x + zs[d+1]*xv.y + zs[d+2]*xv.z + zs[d+3]*xv.w;
  }
  reg[(size_t)r*NPP + p] = acc;
}

// ---------------- batched scores: S[b] = Q_b K_b^T (bf16 MFMA, fp32 out) ----------------
__global__ __launch_bounds__(256) void k_scores(const u16* __restrict__ qkv, float* __restrict__ S) {
  __shared__ u16 Qs[64*40];
  __shared__ u16 Ks[64*40];
  const int tid = threadIdx.x, wid = tid >> 6, lane = tid & 63;
  const int b = blockIdx.x >> 4, tile = blockIdx.x & 15;
  const int i0 = (tile >> 2) * 64, j0 = (tile & 3) * 64;
  const size_t base = (size_t)b * NT * LDQ;
  const int wr = (wid >> 1) * 32, wc = (wid & 1) * 32;
  const int fr = lane & 15, fg = lane >> 4;
  const int sr = tid >> 2, sc = (tid & 3) * 8;
  const int tq = min(i0 + sr, NT-1), tk = min(j0 + sr, NT-1);
  const u16* gq = qkv + base + (size_t)tq * LDQ + sc;
  const u16* gk = qkv + base + (size_t)tk * LDQ + 768 + sc;
  f32x4 acc[2][2] = {};
  for (int k0 = 0; k0 < 768; k0 += 32) {
    bf16x8 qa = *(const bf16x8*)(gq + k0);
    bf16x8 ka = *(const bf16x8*)(gk + k0);
    *(bf16x8*)&Qs[sr*40 + sc] = qa;
    *(bf16x8*)&Ks[sr*40 + sc] = ka;
    __syncthreads();
    bf16x8 av[2], bv[2];
    av[0] = *(const bf16x8*)&Qs[(wr      + fr)*40 + fg*8];
    av[1] = *(const bf16x8*)&Qs[(wr + 16 + fr)*40 + fg*8];
    bv[0] = *(const bf16x8*)&Ks[(wc      + fr)*40 + fg*8];
    bv[1] = *(const bf16x8*)&Ks[(wc + 16 + fr)*40 + fg*8];
    acc[0][0] = mfma16(av[0], bv[0], acc[0][0]);
    acc[0][1] = mfma16(av[0], bv[1], acc[0][1]);
    acc[1][0] = mfma16(av[1], bv[0], acc[1][0]);
    acc[1][1] = mfma16(av[1], bv[1], acc[1][1]);
    __syncthreads();
  }
  #pragma unroll
  for (int m = 0; m < 2; ++m)
    #pragma unroll
    for (int n = 0; n < 2; ++n)
      #pragma unroll
      for (int j = 0; j < 4; ++j) {
        int i  = i0 + wr + m*16 + fg*4 + j;
        int jj = j0 + wc + n*16 + fr;
        if (i < NT && jj < NT)
          S[(size_t)b*NT*NT + (size_t)i*NT + jj] = acc[m][n][j];
      }
}

// ---------------- argmax + gaussian mask, overwrite concept-row region in S (fp32 exact) ----------------
__global__ __launch_bounds__(64) void k_mask(const float* __restrict__ reg, float* __restrict__ S) {
  const int r = blockIdx.x, b = r >> 3, c = r & 7;
  const int lane = threadIdx.x;
  float best = -1e30f; int bi = 0;
  #pragma unroll
  for (int q = 0; q < 4; ++q) {
    int p = lane + q*64;
    if (p < NPP) {
      float v = reg[(size_t)r*NPP + p];
      if (v > best) { best = v; bi = p; }
    }
  }
  for (int off = 32; off; off >>= 1) {
    float ov = __shfl_xor(best, off);
    int   oi = __shfl_xor(bi, off);
    if (ov > best || (ov == best && oi < bi)) { best = ov; bi = oi; }
  }
  // faithful to reference: center is (h = loc%14, w = loc//14)  [transposed meshgrid]
  const float mx = (float)(bi % 14), my = (float)(bi / 14);
  float* Sr = S + ((size_t)b*NT + 197 + c) * NT + 1;
  #pragma unroll
  for (int q = 0; q < 4; ++q) {
    int p = lane + q*64;
    if (p < NPP) {
      float h = (float)(p / 14), w = (float)(p % 14);
      float d2 = (h - mx)*(h - mx) + (w - my)*(w - my);
      Sr[p] = reg[(size_t)r*NPP + p] * __expf(-2.0f * d2);   // 1/(2*sigma^2)=2, g_max=1
    }
  }
}

// ---------------- softmax per row: fp32 in-place (S becomes final attn probs) ----------------
__global__ __launch_bounds__(256) void k_softmax(float* __restrict__ S) {
  const int row = blockIdx.x * 4 + (threadIdx.x >> 6);
  const int lane = threadIdx.x & 63;
  float* sr = S + (size_t)row * NT;
  float v[4];
  #pragma unroll
  for (int q = 0; q < 4; ++q) {
    int p = lane + q*64;
    v[q] = (p < NT) ? sr[p] * SCL : -1e30f;
  }
  float m = fmaxf(fmaxf(v[0], v[1]), fmaxf(v[2], v[3]));
  for (int off = 32; off; off >>= 1) m = fmaxf(m, __shfl_xor(m, off));
  float e[4], s = 0.f;
  #pragma unroll
  for (int q = 0; q < 4; ++q) {
    int p = lane + q*64;
    e[q] = (p < NT) ? __expf(v[q] - m) : 0.f;
    s += e[q];
  }
  for (int off = 32; off; off >>= 1) s += __shfl_xor(s, off);
  const float inv = 1.0f / s;
  #pragma unroll
  for (int q = 0; q < 4; ++q) {
    int p = lane + q*64;
    if (p < NT) sr[p] = e[q] * inv;
  }
}

// ---------------- batched PV: out[b] = P_b V_b, direct from S (fp32) and qkv (V part) ----------------
// v2: V staged TRANSPOSED in LDS (Vt_s[e][k], pad 40) via 8 ds_write_b16 with XOR-swizzled
// k-column (k ^= ((e>>3)&3)<<3, breaks the 8-lane/bank pile-up), then B-fragments are two
// vector ds_read_b128 per n (swizzle reproduced; 16B aligned). A (P) staging as before.
__global__ __launch_bounds__(256) void k_pv(const float* __restrict__ S, const u16* __restrict__ qkv,
                                            float* __restrict__ out) {
  __shared__ u16 Ps[64*40];    // [i-row][k]
  __shared__ u16 Vt_s[64*40];  // [e][k] transposed, swizzled
  const int tid = threadIdx.x, wid = tid >> 6, lane = tid & 63;
  const int b = blockIdx.x / 48, t = blockIdx.x % 48;
  const int i0 = (t / 12) * 64, e0 = (t % 12) * 64;
  const int wr = (wid >> 1) * 32, wc = (wid & 1) * 32;
  const int fr = lane & 15, fg = lane >> 4;
  const int sr = tid >> 2, sc = (tid & 3) * 8;       // P staging: 64 rows x 32 k
  const int vr = tid >> 3, vebase = (tid & 7) * 8;   // V staging: 32 k-rows x 64 e
  const int vks = vr ^ ((tid & 3) << 3);             // swizzled k-col (== vr ^ swz(e) for this thread's e's)
  const int ip = min(i0 + sr, NT-1);
  const float* Sp = S + ((size_t)b*NT + ip) * NT;
  // B-fragment read bases (constant per lane across iters)
  const int er0 = wc + fr, er1 = wc + 16 + fr;
  const int kc0 = (fg*8) ^ (((er0 >> 3) & 3) << 3);
  const int kc1 = (fg*8) ^ (((er1 >> 3) & 3) << 3);
  f32x4 acc[2][2] = {};
  for (int k0 = 0; k0 < 224; k0 += 32) {
    // stage P (fp32 -> bf16), zero-pad k >= 205
    union { u16 h[8]; uint4 v; } pr_;
    #pragma unroll
    for (int j = 0; j < 8; ++j) {
      int k = k0 + sc + j;
      pr_.h[j] = (k < NT) ? f2bf(Sp[k]) : (u16)0;
    }
    *(uint4*)&Ps[sr*40 + sc] = pr_.v;
    // stage V rows k0+vr transposed (clamped; garbage rows killed by P=0 pad)
    const int kv = min(k0 + vr, NT-1);
    bf16x8 vv = *(const bf16x8*)&qkv[((size_t)b*NT + kv)*LDQ + 1536 + e0 + vebase];
    #pragma unroll
    for (int j = 0; j < 8; ++j) Vt_s[(vebase + j)*40 + vks] = (u16)vv[j];
    __syncthreads();
    bf16x8 av[2], bv[2];
    av[0] = *(const bf16x8*)&Ps[(wr      + fr)*40 + fg*8];
    av[1] = *(const bf16x8*)&Ps[(wr + 16 + fr)*40 + fg*8];
    bv[0] = *(const bf16x8*)&Vt_s[er0*40 + kc0];
    bv[1] = *(const bf16x8*)&Vt_s[er1*40 + kc1];
    acc[0][0] = mfma16(av[0], bv[0], acc[0][0]);
    acc[0][1] = mfma16(av[0], bv[1], acc[0][1]);
    acc[1][0] = mfma16(av[1], bv[0], acc[1][0]);
    acc[1][1] = mfma16(av[1], bv[1], acc[1][1]);
    __syncthreads();
  }
  #pragma unroll
  for (int m = 0; m < 2; ++m)
    #pragma unroll
    for (int n = 0; n < 2; ++n)
      #pragma unroll
      for (int j = 0; j < 4; ++j) {
        int i = i0 + wr + m*16 + fg*4 + j;
        int e = e0 + wc + n*16 + fr;
        if (i < NT)
          out[((size_t)b*NT + i)*DIMD + e] = acc[m][n][j];
      }
}

extern "C" void kernel_launch(void* const* d_in, const int* in_sizes, int n_in,
                              void* d_out, int out_size, void* d_ws, size_t ws_size,
                              hipStream_t stream) {
  const float* x  = (const float*)d_in[0];
  const float* Wq = (const float*)d_in[1];
  const float* Wk = (const float*)d_in[2];
  const float* Wv = (const float*)d_in[3];
  char* ws = (char*)d_ws;
  char* ob = (char*)d_out;

  u16*   wb   = (u16*)(ws + WS_WB);     // [2304][768] bf16: Wq|Wk|Wv
  u16*   qkv  = (u16*)(ws + WS_QKV);    // [52480][2304] bf16 (live until k_pv done)

  float* S    = (float*)ob;             // [256][205][205] scores -> final attn probs
  float* outp = (float*)(ob + DO_OUT);  // [256][205][768] final output (direct)
  u16*   xb   = (u16*)(ob + DO_XB);     // bf16 x (temp, dead after k_qkv)
  float* Mm   = (float*)(ob + DO_M);    // [768][768] fp32 Wq^T*Wk
  float* zz   = (float*)(ob + DO_Z);    // [2048][768] fp32 Xc*M
  float* reg  = (float*)(ob + DO_REG);  // [2048][196] fp32 region scores (dead after k_mask)

  // 1) casts to bf16
  k_cast<<<19680, 256, 0, stream>>>(x,  xb, 5038080);
  k_cast<<<288,   256, 0, stream>>>(Wq, wb,           73728);
  k_cast<<<288,   256, 0, stream>>>(Wk, wb + 589824,  73728);
  k_cast<<<288,   256, 0, stream>>>(Wv, wb + 1179648, 73728);
  // 2) fused QKV projection (bf16 MFMA)
  k_qkv<<<7380, 256, 0, stream>>>(xb, wb, qkv);
  // 3) exact fp32 path for argmax region: M = Wq^T*Wk ; zz = Xc*M ; reg = zz*Xp^T
  k_gemm32<1, false><<<144, 256, 0, stream>>>(Wq, Wk, Mm, 768, 768, 768, 768, 12);
  k_gemm32<2, false><<<384, 256, 0, stream>>>(x,  Mm, zz, 768, 768, 768, 768, 12);
  k_region<<<2048, 256, 0, stream>>>(zz, x, reg);
  // 4) full attention scores (bf16 MFMA, fp32 into d_out)
  k_scores<<<4096, 256, 0, stream>>>(qkv, S);
  // 5) argmax + gaussian mask overwrite (fp32 exact)
  k_mask<<<2048, 64, 0, stream>>>(reg, S);
  // 6) softmax in place (S becomes the final attn output)
  k_softmax<<<13120, 256, 0, stream>>>(S);
  // 7) PV directly from S (fp32 probs) + qkv V-part, writing final out region
  k_pv<<<12288, 256, 0, stream>>>(S, qkv, outp);
}

// Round 5
// 725.681 us; speedup vs baseline: 1.1457x; 1.1445x over previous
//
#include <hip/hip_runtime.h>
#include <hip/hip_bf16.h>

// ---------------- problem constants ----------------
#define NB   256        // batch
#define NT   205        // tokens per batch (1 CLS + 196 patches + 8 concept)
#define DIMD 768
#define NCC  8
#define NPP  196
#define LDY  1536       // yv row stride (Y | V concatenated)
#define SCL  0.03608439182435161f   // 768^-0.5

using u16 = unsigned short;
using u32 = unsigned int;
using bf16x8 = __attribute__((ext_vector_type(8))) short;
using f32x4  = __attribute__((ext_vector_type(4))) float;

// ---------------- buffer byte offsets ----------------
// d_ws:  wb[1536x768 bf16: Mt_b | Wv_b] | yv[52480x1536 bf16]  (max 164,757,504 B < evidenced-safe 245 MB)
#define WS_WB   0ul
#define WS_YV   3538944ul
// d_out: [0,43033600) = attn fp32 (final, written once by k_sms).
//        [43033600,204129280) = out fp32 (final, written by k_pv last).
//        Temporaries in the tail (all dead before k_pv writes):
//          xb bf16 x [52480x768]  (live until k_sms)      @ +43033600  (ends 123,642,880)
//          Mt fp32 [768x768] = Wk^T*Wq = M^T              @ +143696896
//          zz fp32 [2048x768], reg fp32 [2048x196]        @ +149988352 / +156279808
//          regm fp32 [2048x196] masked region values      @ +157885440 (ends 159,491,072)
#define DO_OUT  43033600ul
#define DO_XB   43033600ul
#define DO_M    143696896ul
#define DO_Z    149988352ul
#define DO_REG  156279808ul
#define DO_REGM 157885440ul

__device__ __forceinline__ u16 f2bf(float f) {
  u32 u = __float_as_uint(f);
  u += 0x7FFFu + ((u >> 16) & 1u);
  return (u16)(u >> 16);
}

__device__ __forceinline__ void gld16(const void* g, void* l) {
  __builtin_amdgcn_global_load_lds((const __attribute__((address_space(1))) u32*)g,
                                   (__attribute__((address_space(3))) u32*)l, 16, 0, 0);
}

__device__ __forceinline__ f32x4 mfma16(bf16x8 a, bf16x8 b, f32x4 c) {
  return __builtin_amdgcn_mfma_f32_16x16x32_bf16(a, b, c, 0, 0, 0);
}

// ---------------- fp32 -> bf16 cast, 8 elems/thread ----------------
__global__ __launch_bounds__(256) void k_cast(const float* __restrict__ s, u16* __restrict__ d, int n8) {
  int i = blockIdx.x * 256 + threadIdx.x;
  if (i >= n8) return;
  const float4* s4 = (const float4*)s;
  float4 a = s4[2*(size_t)i], b = s4[2*(size_t)i + 1];
  union { u16 h[8]; uint4 v; } r;
  r.h[0]=f2bf(a.x); r.h[1]=f2bf(a.y); r.h[2]=f2bf(a.z); r.h[3]=f2bf(a.w);
  r.h[4]=f2bf(b.x); r.h[5]=f2bf(b.y); r.h[6]=f2bf(b.z); r.h[7]=f2bf(b.w);
  *(uint4*)(d + 8*(size_t)i) = r.v;
}

// ---------------- big Y|V GEMM: C[52480,1536] = A[52480,768] * Bt[1536,768]^T (bf16) ----------------
// Bt rows 0-767 = Mt_b (so cols 0-767 = Y = X*M); rows 768-1535 = Wv_b (cols = V = X*Wv^T).
__global__ __launch_bounds__(256) void k_yv(const u16* __restrict__ A, const u16* __restrict__ Bt, u16* __restrict__ C) {
  __shared__ u16 As[128*32];
  __shared__ u16 Bs[128*32];
  const int tid = threadIdx.x, wid = tid >> 6, lane = tid & 63;
  const int bm = blockIdx.x / 12, bn = blockIdx.x % 12;
  const size_t m0 = (size_t)bm * 128;
  const int n0 = bn * 128;
  const int wr = (wid >> 1) * 64, wc = (wid & 1) * 64;
  const int fr = lane & 15, fg = lane >> 4;
  const int eb0 = (wid*2+0)*512, eb1 = (wid*2+1)*512;
  const int e0 = eb0 + lane*8, e1 = eb1 + lane*8;
  const int r0 = e0 >> 5, c0 = e0 & 31, r1 = e1 >> 5, c1 = e1 & 31;
  f32x4 acc[4][4] = {};
  for (int k0 = 0; k0 < 768; k0 += 32) {
    gld16(A + (m0 + r0)*768 + k0 + c0, (char*)As + 2*eb0);
    gld16(A + (m0 + r1)*768 + k0 + c1, (char*)As + 2*eb1);
    gld16(Bt + (size_t)(n0 + r0)*768 + k0 + c0, (char*)Bs + 2*eb0);
    gld16(Bt + (size_t)(n0 + r1)*768 + k0 + c1, (char*)Bs + 2*eb1);
    __syncthreads();
    bf16x8 av[4], bv[4];
    #pragma unroll
    for (int m = 0; m < 4; ++m) av[m] = *(const bf16x8*)&As[(wr + m*16 + fr)*32 + fg*8];
    #pragma unroll
    for (int n = 0; n < 4; ++n) bv[n] = *(const bf16x8*)&Bs[(wc + n*16 + fr)*32 + fg*8];
    #pragma unroll
    for (int m = 0; m < 4; ++m)
      #pragma unroll
      for (int n = 0; n < 4; ++n)
        acc[m][n] = mfma16(av[m], bv[n], acc[m][n]);
    __syncthreads();
  }
  #pragma unroll
  for (int m = 0; m < 4; ++m) {
    #pragma unroll
    for (int j = 0; j < 4; ++j) {
      size_t row = m0 + wr + m*16 + fg*4 + j;
      u16* cp = C + row*LDY + n0 + wc;
      #pragma unroll
      for (int n = 0; n < 4; ++n) cp[n*16 + fr] = f2bf(acc[m][n][j]);
    }
  }
}

// ---------------- fp32 tiled GEMM (64x64 tile, 4x4/thread) ----------------
// AM: 0 = A stored [M,K]; 1 = A stored [K,M] (transposed); 2 = [M,K] with concept-row gather.
// BT: true = B stored [N,K]; false = [K,N].
template<int AM, bool BT>
__global__ __launch_bounds__(256) void k_gemm32(const float* __restrict__ A, const float* __restrict__ Bm,
                                                float* __restrict__ C, int lda, int ldb, int ldc,
                                                int K, int nbn) {
  __shared__ float As[16][68];
  __shared__ float Bs[16][68];
  const int tid = threadIdx.x;
  const int m0 = (blockIdx.x / nbn) * 64, n0 = (blockIdx.x % nbn) * 64;
  const int ty = tid >> 4, tx = tid & 15;
  const int sr = tid >> 2, sk = (tid & 3) * 4;
  float acc[4][4] = {};
  for (int k0 = 0; k0 < K; k0 += 16) {
    if (AM == 1) {
      const int ak = tid >> 4, am = (tid & 15) * 4;
      float4 av = *(const float4*)&A[(size_t)(k0 + ak) * lda + m0 + am];
      *(float4*)&As[ak][am] = av;
    } else {
      size_t arow = (size_t)(m0 + sr);
      if (AM == 2) arow = (arow >> 3) * 205 + 197 + (arow & 7);
      float4 av = *(const float4*)&A[arow * lda + k0 + sk];
      As[sk+0][sr] = av.x; As[sk+1][sr] = av.y; As[sk+2][sr] = av.z; As[sk+3][sr] = av.w;
    }
    if (BT) {
      float4 bv = *(const float4*)&Bm[(size_t)(n0 + sr) * ldb + k0 + sk];
      Bs[sk+0][sr] = bv.x; Bs[sk+1][sr] = bv.y; Bs[sk+2][sr] = bv.z; Bs[sk+3][sr] = bv.w;
    } else {
      const int bk = tid >> 4, bn4 = (tid & 15) * 4;
      float4 bv = *(const float4*)&Bm[(size_t)(k0 + bk) * ldb + n0 + bn4];
      *(float4*)&Bs[bk][bn4] = bv;
    }
    __syncthreads();
    #pragma unroll
    for (int kk = 0; kk < 16; ++kk) {
      float4 a4 = *(const float4*)&As[kk][ty*4];
      float4 b4 = *(const float4*)&Bs[kk][tx*4];
      float a[4] = {a4.x, a4.y, a4.z, a4.w};
      float b[4] = {b4.x, b4.y, b4.z, b4.w};
      #pragma unroll
      for (int i = 0; i < 4; ++i)
        #pragma unroll
        for (int j = 0; j < 4; ++j) acc[i][j] += a[i]*b[j];
    }
    __syncthreads();
  }
  #pragma unroll
  for (int i = 0; i < 4; ++i) {
    float4 o = {acc[i][0], acc[i][1], acc[i][2], acc[i][3]};
    *(float4*)&C[(size_t)(m0 + ty*4 + i) * ldc + n0 + tx*4] = o;
  }
}

// ---------------- region scores: reg[r,p] = z[r,:] . x[b, 1+p, :]  (fp32 exact path) ----------------
__global__ __launch_bounds__(256) void k_region(const float* __restrict__ z, const float* __restrict__ x,
                                                float* __restrict__ reg) {
  const int r = blockIdx.x, b = r >> 3;
  __shared__ float zs[768];
  for (int i = threadIdx.x; i < 768; i += 256) zs[i] = z[(size_t)r*768 + i];
  __syncthreads();
  const int p = threadIdx.x;
  if (p >= NPP) return;
  const float* xp = x + ((size_t)b*NT + 1 + p) * DIMD;
  float acc = 0.f;
  #pragma unroll 8
  for (int d = 0; d < 768; d += 4) {
    float4 xv = *(const float4*)&xp[d];
    acc += zs[d]*xv.x + zs[d+1]*xv.y + zs[d+2]*xv.z + zs[d+3]*xv.w;
  }
  reg[(size_t)r*NPP + p] = acc;
}

// ---------------- argmax + gaussian mask -> regm (standalone masked-region values, fp32 exact) ------
__global__ __launch_bounds__(64) void k_maskreg(const float* __restrict__ reg, float* __restrict__ regm) {
  const int r = blockIdx.x;
  const int lane = threadIdx.x;
  float best = -1e30f; int bi = 0;
  #pragma unroll
  for (int q = 0; q < 4; ++q) {
    int p = lane + q*64;
    if (p < NPP) {
      float v = reg[(size_t)r*NPP + p];
      if (v > best) { best = v; bi = p; }
    }
  }
  for (int off = 32; off; off >>= 1) {
    float ov = __shfl_xor(best, off);
    int   oi = __shfl_xor(bi, off);
    if (ov > best || (ov == best && oi < bi)) { best = ov; bi = oi; }
  }
  // faithful to reference: center is (h = loc%14, w = loc//14)  [transposed meshgrid]
  const float mx = (float)(bi % 14), my = (float)(bi / 14);
  #pragma unroll
  for (int q = 0; q < 4; ++q) {
    int p = lane + q*64;
    if (p < NPP) {
      float h = (float)(p / 14), w = (float)(p % 14);
      float d2 = (h - mx)*(h - mx) + (w - my)*(w - my);
      regm[(size_t)r*NPP + p] = reg[(size_t)r*NPP + p] * __expf(-2.0f * d2);  // 1/(2σ²)=2, g_max=1
    }
  }
}

// ---------------- fused scores+mask+softmax: S[b,i,:] = softmax(mask(Y_b[i]·X_b^T)·SCL) ------------
// One block = 64 full rows of one batch. acc[13] covers all 208 (pad) columns; row-softmax via
// 4 shuffle-xors among the 16 lanes sharing fg. Concept rows pull exact fp32 masked values (regm).
__global__ __launch_bounds__(256) void k_sms(const u16* __restrict__ yv, const u16* __restrict__ xb,
                                             const float* __restrict__ regm, float* __restrict__ S) {
  __shared__ u16 Ys[64*40];
  __shared__ u16 Xs[208*40];
  const int tid = threadIdx.x, wid = tid >> 6, lane = tid & 63;
  const int b = blockIdx.x >> 2, it = blockIdx.x & 3;
  const int i0 = it * 64;
  const int fr = lane & 15, fg = lane >> 4;
  const int sr = tid >> 2, sc = (tid & 3) * 8;
  const size_t xbase = (size_t)b * NT;
  const u16* gy = yv + (xbase + (size_t)min(i0 + sr, NT-1)) * LDY + sc;
  const u16* gx = xb + xbase * DIMD;
  f32x4 acc[13] = {};
  for (int k0 = 0; k0 < 768; k0 += 32) {
    *(bf16x8*)&Ys[sr*40 + sc] = *(const bf16x8*)(gy + k0);
    *(bf16x8*)&Xs[(sr      )*40 + sc] = *(const bf16x8*)&gx[(size_t)(sr      )*DIMD + k0 + sc];
    *(bf16x8*)&Xs[(sr +  64)*40 + sc] = *(const bf16x8*)&gx[(size_t)(sr +  64)*DIMD + k0 + sc];
    *(bf16x8*)&Xs[(sr + 128)*40 + sc] = *(const bf16x8*)&gx[(size_t)(sr + 128)*DIMD + k0 + sc];
    if (sr < 16)
      *(bf16x8*)&Xs[(sr + 192)*40 + sc] = *(const bf16x8*)&gx[(size_t)min(sr + 192, NT-1)*DIMD + k0 + sc];
    __syncthreads();
    bf16x8 a = *(const bf16x8*)&Ys[(wid*16 + fr)*40 + fg*8];
    #pragma unroll
    for (int n = 0; n < 13; ++n) {
      bf16x8 bv = *(const bf16x8*)&Xs[(n*16 + fr)*40 + fg*8];
      acc[n] = mfma16(a, bv, acc[n]);
    }
    __syncthreads();
  }
  // epilogue: per accumulator row jj -> global row gi
  #pragma unroll
  for (int jj = 0; jj < 4; ++jj) {
    const int gi = i0 + wid*16 + fg*4 + jj;
    if (gi >= 197 && gi < NT) {                 // concept row: exact masked region, cols 1..196
      const float* rm = regm + ((size_t)b*NCC + (gi - 197)) * NPP;
      #pragma unroll
      for (int n = 0; n < 13; ++n) {
        int c = n*16 + fr;
        if (c >= 1 && c <= NPP) acc[n][jj] = rm[c - 1];
      }
    }
    float m = -1e30f;
    #pragma unroll
    for (int n = 0; n < 13; ++n) {
      int c = n*16 + fr;
      float v = (c < NT) ? acc[n][jj] * SCL : -1e30f;
      acc[n][jj] = v;
      m = fmaxf(m, v);
    }
    m = fmaxf(m, __shfl_xor(m, 1)); m = fmaxf(m, __shfl_xor(m, 2));
    m = fmaxf(m, __shfl_xor(m, 4)); m = fmaxf(m, __shfl_xor(m, 8));
    float s = 0.f;
    #pragma unroll
    for (int n = 0; n < 13; ++n) {
      int c = n*16 + fr;
      float e = (c < NT) ? __expf(acc[n][jj] - m) : 0.f;
      acc[n][jj] = e;
      s += e;
    }
    s += __shfl_xor(s, 1); s += __shfl_xor(s, 2);
    s += __shfl_xor(s, 4); s += __shfl_xor(s, 8);
    const float inv = 1.0f / s;
    if (gi < NT) {
      float* So = S + ((size_t)b*NT + gi) * NT;
      #pragma unroll
      for (int n = 0; n < 13; ++n) {
        int c = n*16 + fr;
        if (c < NT) So[c] = acc[n][jj] * inv;
      }
    }
  }
}

// ---------------- batched PV: out[b] = P_b V_b, from S (fp32 probs) and yv (V at col 768) ----------
__global__ __launch_bounds__(256) void k_pv(const float* __restrict__ S, const u16* __restrict__ yv,
                                            float* __restrict__ out) {
  __shared__ u16 Ps[64*40];    // [i-row][k]
  __shared__ u16 Vt_s[64*40];  // [e][k] transposed, swizzled
  const int tid = threadIdx.x, wid = tid >> 6, lane = tid & 63;
  const int b = blockIdx.x / 48, t = blockIdx.x % 48;
  const int i0 = (t / 12) * 64, e0 = (t % 12) * 64;
  const int wr = (wid >> 1) * 32, wc = (wid & 1) * 32;
  const int fr = lane & 15, fg = lane >> 4;
  const int sr = tid >> 2, sc = (tid & 3) * 8;       // P staging: 64 rows x 32 k
  const int vr = tid >> 3, vebase = (tid & 7) * 8;   // V staging: 32 k-rows x 64 e
  const int vks = vr ^ ((tid & 3) << 3);             // swizzled k-col
  const int ip = min(i0 + sr, NT-1);
  const float* Sp = S + ((size_t)b*NT + ip) * NT;
  const int er0 = wc + fr, er1 = wc + 16 + fr;
  const int kc0 = (fg*8) ^ (((er0 >> 3) & 3) << 3);
  const int kc1 = (fg*8) ^ (((er1 >> 3) & 3) << 3);
  f32x4 acc[2][2] = {};
  for (int k0 = 0; k0 < 224; k0 += 32) {
    union { u16 h[8]; uint4 v; } pr_;
    #pragma unroll
    for (int j = 0; j < 8; ++j) {
      int k = k0 + sc + j;
      pr_.h[j] = (k < NT) ? f2bf(Sp[k]) : (u16)0;
    }
    *(uint4*)&Ps[sr*40 + sc] = pr_.v;
    const int kv = min(k0 + vr, NT-1);
    bf16x8 vv = *(const bf16x8*)&yv[((size_t)b*NT + kv)*LDY + 768 + e0 + vebase];
    #pragma unroll
    for (int j = 0; j < 8; ++j) Vt_s[(vebase + j)*40 + vks] = (u16)vv[j];
    __syncthreads();
    bf16x8 av[2], bv[2];
    av[0] = *(const bf16x8*)&Ps[(wr      + fr)*40 + fg*8];
    av[1] = *(const bf16x8*)&Ps[(wr + 16 + fr)*40 + fg*8];
    bv[0] = *(const bf16x8*)&Vt_s[er0*40 + kc0];
    bv[1] = *(const bf16x8*)&Vt_s[er1*40 + kc1];
    acc[0][0] = mfma16(av[0], bv[0], acc[0][0]);
    acc[0][1] = mfma16(av[0], bv[1], acc[0][1]);
    acc[1][0] = mfma16(av[1], bv[0], acc[1][0]);
    acc[1][1] = mfma16(av[1], bv[1], acc[1][1]);
    __syncthreads();
  }
  #pragma unroll
  for (int m = 0; m < 2; ++m)
    #pragma unroll
    for (int n = 0; n < 2; ++n)
      #pragma unroll
      for (int j = 0; j < 4; ++j) {
        int i = i0 + wr + m*16 + fg*4 + j;
        int e = e0 + wc + n*16 + fr;
        if (i < NT)
          out[((size_t)b*NT + i)*DIMD + e] = acc[m][n][j];
      }
}

extern "C" void kernel_launch(void* const* d_in, const int* in_sizes, int n_in,
                              void* d_out, int out_size, void* d_ws, size_t ws_size,
                              hipStream_t stream) {
  const float* x  = (const float*)d_in[0];
  const float* Wq = (const float*)d_in[1];
  const float* Wk = (const float*)d_in[2];
  const float* Wv = (const float*)d_in[3];
  char* ws = (char*)d_ws;
  char* ob = (char*)d_out;

  u16*   wb   = (u16*)(ws + WS_WB);     // [1536][768] bf16: Mt | Wv
  u16*   yv   = (u16*)(ws + WS_YV);     // [52480][1536] bf16 (Y | V), live until k_pv done

  float* S    = (float*)ob;             // [256][205][205] final attn probs (written once by k_sms)
  float* outp = (float*)(ob + DO_OUT);  // [256][205][768] final output (k_pv, last writer)
  u16*   xb   = (u16*)(ob + DO_XB);     // bf16 x (live until k_sms done)
  float* Mt   = (float*)(ob + DO_M);    // [768][768] fp32 Wk^T*Wq = M^T
  float* zz   = (float*)(ob + DO_Z);    // [2048][768] fp32 Xc*M
  float* reg  = (float*)(ob + DO_REG);  // [2048][196] fp32 raw region scores
  float* regm = (float*)(ob + DO_REGM); // [2048][196] fp32 masked region values

  // 1) cast x; exact Mt = Wk^T*Wq (fp32)
  k_cast<<<19680, 256, 0, stream>>>(x, xb, 5038080);
  k_gemm32<1, false><<<144, 256, 0, stream>>>(Wk, Wq, Mt, 768, 768, 768, 768, 12);
  // 2) weight buffer: rows 0-767 = bf16(Mt), rows 768-1535 = bf16(Wv)
  k_cast<<<288, 256, 0, stream>>>(Mt, wb,          73728);
  k_cast<<<288, 256, 0, stream>>>(Wv, wb + 589824, 73728);
  // 3) fused Y|V GEMM (bf16 MFMA): Y = X*M, V = X*Wv^T
  k_yv<<<4920, 256, 0, stream>>>(xb, wb, yv);
  // 4) exact fp32 argmax path: zz = Xc*M (via Mt rows), reg = zz*Xp^T, regm = mask(reg)
  k_gemm32<2, true><<<384, 256, 0, stream>>>(x, Mt, zz, 768, 768, 768, 768, 12);
  k_region<<<2048, 256, 0, stream>>>(zz, x, reg);
  k_maskreg<<<2048, 64, 0, stream>>>(reg, regm);
  // 5) fused scores+mask+softmax -> final attn probs (S written once)
  k_sms<<<1024, 256, 0, stream>>>(yv, xb, regm, S);
  // 6) PV -> final out region
  k_pv<<<12288, 256, 0, stream>>>(S, yv, outp);
}

// Round 6
// 655.789 us; speedup vs baseline: 1.2678x; 1.1066x over previous
//
#include <hip/hip_runtime.h>
#include <hip/hip_bf16.h>

// ---------------- problem constants ----------------
#define NB   256        // batch
#define NT   205        // tokens per batch (1 CLS + 196 patches + 8 concept)
#define DIMD 768
#define NCC  8
#define NPP  196
#define LDY  1536       // yv row stride (Y | V concatenated)
#define SCL  0.03608439182435161f   // 768^-0.5

using u16 = unsigned short;
using u32 = unsigned int;
using bf16x8 = __attribute__((ext_vector_type(8))) short;
using f32x4  = __attribute__((ext_vector_type(4))) float;

// ---------------- buffer byte offsets ----------------
// d_ws:  wb[1536x768 bf16: Mt_b | Wv_b] | yv[52480x1536 bf16]  (max 164,757,504 B < evidenced-safe 245 MB)
#define WS_WB   0ul
#define WS_YV   3538944ul
// d_out: [0,43033600) = attn fp32 (final, written once by k_sms).
//        [43033600,204129280) = out fp32 (final, written by k_pv last).
//        Temporaries in the tail (all dead before k_pv writes):
//          xb bf16 x [52480x768]  (live until k_sms)      @ +43033600  (ends 123,642,880)
//          Mt fp32 [768x768] = Wk^T*Wq = M^T              @ +143696896
//          zz fp32 [2048x768], reg fp32 [2048x196]        @ +149988352 / +156279808
//          regm fp32 [2048x196] masked region values      @ +157885440 (ends 159,491,072)
#define DO_OUT  43033600ul
#define DO_XB   43033600ul
#define DO_M    143696896ul
#define DO_Z    149988352ul
#define DO_REG  156279808ul
#define DO_REGM 157885440ul

__device__ __forceinline__ u16 f2bf(float f) {
  u32 u = __float_as_uint(f);
  u += 0x7FFFu + ((u >> 16) & 1u);
  return (u16)(u >> 16);
}

__device__ __forceinline__ void gld16(const void* g, void* l) {
  __builtin_amdgcn_global_load_lds((const __attribute__((address_space(1))) u32*)g,
                                   (__attribute__((address_space(3))) u32*)l, 16, 0, 0);
}

__device__ __forceinline__ f32x4 mfma16(bf16x8 a, bf16x8 b, f32x4 c) {
  return __builtin_amdgcn_mfma_f32_16x16x32_bf16(a, b, c, 0, 0, 0);
}

// ---------------- fp32 -> bf16 cast, 8 elems/thread ----------------
__global__ __launch_bounds__(256) void k_cast(const float* __restrict__ s, u16* __restrict__ d, int n8) {
  int i = blockIdx.x * 256 + threadIdx.x;
  if (i >= n8) return;
  const float4* s4 = (const float4*)s;
  float4 a = s4[2*(size_t)i], b = s4[2*(size_t)i + 1];
  union { u16 h[8]; uint4 v; } r;
  r.h[0]=f2bf(a.x); r.h[1]=f2bf(a.y); r.h[2]=f2bf(a.z); r.h[3]=f2bf(a.w);
  r.h[4]=f2bf(b.x); r.h[5]=f2bf(b.y); r.h[6]=f2bf(b.z); r.h[7]=f2bf(b.w);
  *(uint4*)(d + 8*(size_t)i) = r.v;
}

// ---------------- big Y|V GEMM: C[52480,1536] = A[52480,768] * Bt[1536,768]^T (bf16) ----------------
// Bt rows 0-767 = Mt_b (cols 0-767 = Y = X*M); rows 768-1535 = Wv_b (cols = V = X*Wv^T).
// XCD-chunked swizzle (4920 = 8*615): consecutive swz ids (sharing A-tile) land on one XCD's L2.
__global__ __launch_bounds__(256) void k_yv(const u16* __restrict__ A, const u16* __restrict__ Bt, u16* __restrict__ C) {
  __shared__ u16 As[128*32];
  __shared__ u16 Bs[128*32];
  const int tid = threadIdx.x, wid = tid >> 6, lane = tid & 63;
  const int swz = (blockIdx.x & 7) * 615 + (blockIdx.x >> 3);
  const int bm = swz / 12, bn = swz % 12;
  const size_t m0 = (size_t)bm * 128;
  const int n0 = bn * 128;
  const int wr = (wid >> 1) * 64, wc = (wid & 1) * 64;
  const int fr = lane & 15, fg = lane >> 4;
  const int eb0 = (wid*2+0)*512, eb1 = (wid*2+1)*512;
  const int e0 = eb0 + lane*8, e1 = eb1 + lane*8;
  const int r0 = e0 >> 5, c0 = e0 & 31, r1 = e1 >> 5, c1 = e1 & 31;
  f32x4 acc[4][4] = {};
  for (int k0 = 0; k0 < 768; k0 += 32) {
    gld16(A + (m0 + r0)*768 + k0 + c0, (char*)As + 2*eb0);
    gld16(A + (m0 + r1)*768 + k0 + c1, (char*)As + 2*eb1);
    gld16(Bt + (size_t)(n0 + r0)*768 + k0 + c0, (char*)Bs + 2*eb0);
    gld16(Bt + (size_t)(n0 + r1)*768 + k0 + c1, (char*)Bs + 2*eb1);
    __syncthreads();
    bf16x8 av[4], bv[4];
    #pragma unroll
    for (int m = 0; m < 4; ++m) av[m] = *(const bf16x8*)&As[(wr + m*16 + fr)*32 + fg*8];
    #pragma unroll
    for (int n = 0; n < 4; ++n) bv[n] = *(const bf16x8*)&Bs[(wc + n*16 + fr)*32 + fg*8];
    #pragma unroll
    for (int m = 0; m < 4; ++m)
      #pragma unroll
      for (int n = 0; n < 4; ++n)
        acc[m][n] = mfma16(av[m], bv[n], acc[m][n]);
    __syncthreads();
  }
  #pragma unroll
  for (int m = 0; m < 4; ++m) {
    #pragma unroll
    for (int j = 0; j < 4; ++j) {
      size_t row = m0 + wr + m*16 + fg*4 + j;
      u16* cp = C + row*LDY + n0 + wc;
      #pragma unroll
      for (int n = 0; n < 4; ++n) cp[n*16 + fr] = f2bf(acc[m][n][j]);
    }
  }
}

// ---------------- fp32 tiled GEMM (64x64 tile, 4x4/thread) ----------------
// AM: 0 = A stored [M,K]; 1 = A stored [K,M] (transposed); 2 = [M,K] with concept-row gather.
// BT: true = B stored [N,K]; false = [K,N].
template<int AM, bool BT>
__global__ __launch_bounds__(256) void k_gemm32(const float* __restrict__ A, const float* __restrict__ Bm,
                                                float* __restrict__ C, int lda, int ldb, int ldc,
                                                int K, int nbn) {
  __shared__ float As[16][68];
  __shared__ float Bs[16][68];
  const int tid = threadIdx.x;
  const int m0 = (blockIdx.x / nbn) * 64, n0 = (blockIdx.x % nbn) * 64;
  const int ty = tid >> 4, tx = tid & 15;
  const int sr = tid >> 2, sk = (tid & 3) * 4;
  float acc[4][4] = {};
  for (int k0 = 0; k0 < K; k0 += 16) {
    if (AM == 1) {
      const int ak = tid >> 4, am = (tid & 15) * 4;
      float4 av = *(const float4*)&A[(size_t)(k0 + ak) * lda + m0 + am];
      *(float4*)&As[ak][am] = av;
    } else {
      size_t arow = (size_t)(m0 + sr);
      if (AM == 2) arow = (arow >> 3) * 205 + 197 + (arow & 7);
      float4 av = *(const float4*)&A[arow * lda + k0 + sk];
      As[sk+0][sr] = av.x; As[sk+1][sr] = av.y; As[sk+2][sr] = av.z; As[sk+3][sr] = av.w;
    }
    if (BT) {
      float4 bv = *(const float4*)&Bm[(size_t)(n0 + sr) * ldb + k0 + sk];
      Bs[sk+0][sr] = bv.x; Bs[sk+1][sr] = bv.y; Bs[sk+2][sr] = bv.z; Bs[sk+3][sr] = bv.w;
    } else {
      const int bk = tid >> 4, bn4 = (tid & 15) * 4;
      float4 bv = *(const float4*)&Bm[(size_t)(k0 + bk) * ldb + n0 + bn4];
      *(float4*)&Bs[bk][bn4] = bv;
    }
    __syncthreads();
    #pragma unroll
    for (int kk = 0; kk < 16; ++kk) {
      float4 a4 = *(const float4*)&As[kk][ty*4];
      float4 b4 = *(const float4*)&Bs[kk][tx*4];
      float a[4] = {a4.x, a4.y, a4.z, a4.w};
      float b[4] = {b4.x, b4.y, b4.z, b4.w};
      #pragma unroll
      for (int i = 0; i < 4; ++i)
        #pragma unroll
        for (int j = 0; j < 4; ++j) acc[i][j] += a[i]*b[j];
    }
    __syncthreads();
  }
  #pragma unroll
  for (int i = 0; i < 4; ++i) {
    float4 o = {acc[i][0], acc[i][1], acc[i][2], acc[i][3]};
    *(float4*)&C[(size_t)(m0 + ty*4 + i) * ldc + n0 + tx*4] = o;
  }
}

// ---------------- region scores: reg[r,p] = z[r,:] . x[b, 1+p, :]  (fp32 exact path) ----------------
__global__ __launch_bounds__(256) void k_region(const float* __restrict__ z, const float* __restrict__ x,
                                                float* __restrict__ reg) {
  const int r = blockIdx.x, b = r >> 3;
  __shared__ float zs[768];
  for (int i = threadIdx.x; i < 768; i += 256) zs[i] = z[(size_t)r*768 + i];
  __syncthreads();
  const int p = threadIdx.x;
  if (p >= NPP) return;
  const float* xp = x + ((size_t)b*NT + 1 + p) * DIMD;
  float acc = 0.f;
  #pragma unroll 8
  for (int d = 0; d < 768; d += 4) {
    float4 xv = *(const float4*)&xp[d];
    acc += zs[d]*xv.x + zs[d+1]*xv.y + zs[d+2]*xv.z + zs[d+3]*xv.w;
  }
  reg[(size_t)r*NPP + p] = acc;
}

// ---------------- argmax + gaussian mask -> regm (standalone masked-region values, fp32 exact) ------
__global__ __launch_bounds__(64) void k_maskreg(const float* __restrict__ reg, float* __restrict__ regm) {
  const int r = blockIdx.x;
  const int lane = threadIdx.x;
  float best = -1e30f; int bi = 0;
  #pragma unroll
  for (int q = 0; q < 4; ++q) {
    int p = lane + q*64;
    if (p < NPP) {
      float v = reg[(size_t)r*NPP + p];
      if (v > best) { best = v; bi = p; }
    }
  }
  for (int off = 32; off; off >>= 1) {
    float ov = __shfl_xor(best, off);
    int   oi = __shfl_xor(bi, off);
    if (ov > best || (ov == best && oi < bi)) { best = ov; bi = oi; }
  }
  // faithful to reference: center is (h = loc%14, w = loc//14)  [transposed meshgrid]
  const float mx = (float)(bi % 14), my = (float)(bi / 14);
  #pragma unroll
  for (int q = 0; q < 4; ++q) {
    int p = lane + q*64;
    if (p < NPP) {
      float h = (float)(p / 14), w = (float)(p % 14);
      float d2 = (h - mx)*(h - mx) + (w - my)*(w - my);
      regm[(size_t)r*NPP + p] = reg[(size_t)r*NPP + p] * __expf(-2.0f * d2);  // 1/(2σ²)=2, g_max=1
    }
  }
}

// ---------------- fused scores+mask+softmax: S[b,i,:] = softmax(mask(Y_b[i]·X_b^T)·SCL) ------------
// One block = 64 full rows of one batch; XCD-swizzled so the 4 blocks sharing X_b co-locate.
__global__ __launch_bounds__(256) void k_sms(const u16* __restrict__ yv, const u16* __restrict__ xb,
                                             const float* __restrict__ regm, float* __restrict__ S) {
  __shared__ u16 Ys[64*40];
  __shared__ u16 Xs[208*40];
  const int tid = threadIdx.x, wid = tid >> 6, lane = tid & 63;
  const int swz = (blockIdx.x & 7) * 128 + (blockIdx.x >> 3);
  const int b = swz >> 2, it = swz & 3;
  const int i0 = it * 64;
  const int fr = lane & 15, fg = lane >> 4;
  const int sr = tid >> 2, sc = (tid & 3) * 8;
  const size_t xbase = (size_t)b * NT;
  const u16* gy = yv + (xbase + (size_t)min(i0 + sr, NT-1)) * LDY + sc;
  const u16* gx = xb + xbase * DIMD;
  f32x4 acc[13] = {};
  for (int k0 = 0; k0 < 768; k0 += 32) {
    *(bf16x8*)&Ys[sr*40 + sc] = *(const bf16x8*)(gy + k0);
    *(bf16x8*)&Xs[(sr      )*40 + sc] = *(const bf16x8*)&gx[(size_t)(sr      )*DIMD + k0 + sc];
    *(bf16x8*)&Xs[(sr +  64)*40 + sc] = *(const bf16x8*)&gx[(size_t)(sr +  64)*DIMD + k0 + sc];
    *(bf16x8*)&Xs[(sr + 128)*40 + sc] = *(const bf16x8*)&gx[(size_t)(sr + 128)*DIMD + k0 + sc];
    if (sr < 16)
      *(bf16x8*)&Xs[(sr + 192)*40 + sc] = *(const bf16x8*)&gx[(size_t)min(sr + 192, NT-1)*DIMD + k0 + sc];
    __syncthreads();
    bf16x8 a = *(const bf16x8*)&Ys[(wid*16 + fr)*40 + fg*8];
    #pragma unroll
    for (int n = 0; n < 13; ++n) {
      bf16x8 bv = *(const bf16x8*)&Xs[(n*16 + fr)*40 + fg*8];
      acc[n] = mfma16(a, bv, acc[n]);
    }
    __syncthreads();
  }
  // epilogue: per accumulator row jj -> global row gi
  #pragma unroll
  for (int jj = 0; jj < 4; ++jj) {
    const int gi = i0 + wid*16 + fg*4 + jj;
    if (gi >= 197 && gi < NT) {                 // concept row: exact masked region, cols 1..196
      const float* rm = regm + ((size_t)b*NCC + (gi - 197)) * NPP;
      #pragma unroll
      for (int n = 0; n < 13; ++n) {
        int c = n*16 + fr;
        if (c >= 1 && c <= NPP) acc[n][jj] = rm[c - 1];
      }
    }
    float m = -1e30f;
    #pragma unroll
    for (int n = 0; n < 13; ++n) {
      int c = n*16 + fr;
      float v = (c < NT) ? acc[n][jj] * SCL : -1e30f;
      acc[n][jj] = v;
      m = fmaxf(m, v);
    }
    m = fmaxf(m, __shfl_xor(m, 1)); m = fmaxf(m, __shfl_xor(m, 2));
    m = fmaxf(m, __shfl_xor(m, 4)); m = fmaxf(m, __shfl_xor(m, 8));
    float s = 0.f;
    #pragma unroll
    for (int n = 0; n < 13; ++n) {
      int c = n*16 + fr;
      float e = (c < NT) ? __expf(acc[n][jj] - m) : 0.f;
      acc[n][jj] = e;
      s += e;
    }
    s += __shfl_xor(s, 1); s += __shfl_xor(s, 2);
    s += __shfl_xor(s, 4); s += __shfl_xor(s, 8);
    const float inv = 1.0f / s;
    if (gi < NT) {
      float* So = S + ((size_t)b*NT + gi) * NT;
      #pragma unroll
      for (int n = 0; n < 13; ++n) {
        int c = n*16 + fr;
        if (c < NT) So[c] = acc[n][jj] * inv;
      }
    }
  }
}

// ---------------- batched PV v3: single-stage LDS, one barrier, 28 back-to-back MFMAs --------------
// Stage FULL P tile [64 rows][224 k] (bf16, zero k>=205) and FULL swizzled V^T tile [64 e][224 k],
// then all 2m x 2n x 7k MFMAs with no further barriers.
__global__ __launch_bounds__(256) void k_pv(const float* __restrict__ S, const u16* __restrict__ yv,
                                            float* __restrict__ out) {
  __shared__ u16 Ps[64*232];    // [i-row][k], stride 232 (2-way max bank aliasing)
  __shared__ u16 Vt_s[64*232];  // [e][k] transposed, k XOR-swizzled per 32-chunk
  const int tid = threadIdx.x, wid = tid >> 6, lane = tid & 63;
  const int swz = (blockIdx.x & 7) * 1536 + (blockIdx.x >> 3);
  const int b = swz / 48, t = swz % 48;
  const int i0 = (t / 12) * 64, e0 = (t % 12) * 64;
  const int wr = (wid >> 1) * 32, wc = (wid & 1) * 32;
  const int fr = lane & 15, fg = lane >> 4;
  // ---- stage P: row sr = tid>>2, cols (tid&3)*4 + 16j, j = 0..13 (cols 208..223 forced 0)
  {
    const int sr = tid >> 2, cb = (tid & 3) * 4;
    const int ip = min(i0 + sr, NT-1);
    const float* Sp = S + ((size_t)b*NT + ip) * NT;
    #pragma unroll
    for (int j = 0; j < 14; ++j) {
      const int col = cb + 16*j;
      union { u16 h[4]; uint2 v; } w;
      if (col < NT) {           // may read <=12B past row end (next row) - masked below, in-bounds
        float4 pv = *(const float4*)&Sp[col];
        w.h[0] = (col+0 < NT) ? f2bf(pv.x) : (u16)0;
        w.h[1] = (col+1 < NT) ? f2bf(pv.y) : (u16)0;
        w.h[2] = (col+2 < NT) ? f2bf(pv.z) : (u16)0;
        w.h[3] = (col+3 < NT) ? f2bf(pv.w) : (u16)0;
      } else { w.h[0]=w.h[1]=w.h[2]=w.h[3]=0; }
      *(uint2*)&Ps[sr*232 + col] = w.v;
    }
  }
  // ---- stage V transposed+swizzled: chunks c=0..6, thread (vr=tid>>3, g=tid&7)
  {
    const int vr = tid >> 3, g = tid & 7;
    const int vks = vr ^ ((g & 3) << 3);
    #pragma unroll
    for (int c = 0; c < 7; ++c) {
      const int kv = min(c*32 + vr, NT-1);   // clamped rows produce garbage killed by P=0
      bf16x8 vv = *(const bf16x8*)&yv[((size_t)b*NT + kv)*LDY + 768 + e0 + g*8];
      #pragma unroll
      for (int j = 0; j < 8; ++j) Vt_s[(g*8 + j)*232 + c*32 + vks] = (u16)vv[j];
    }
  }
  __syncthreads();
  // ---- MFMA: av row (wr+m*16+fr), col k*32+fg*8; bv row er, col k*32 + (fg*8 ^ X(er))
  const int er0 = wc + fr, er1 = wc + 16 + fr;
  const int kx0 = (fg*8) ^ (((er0 >> 3) & 3) << 3);
  const int kx1 = (fg*8) ^ (((er1 >> 3) & 3) << 3);
  f32x4 acc[2][2] = {};
  #pragma unroll
  for (int k = 0; k < 7; ++k) {
    bf16x8 av[2], bv[2];
    av[0] = *(const bf16x8*)&Ps[(wr      + fr)*232 + k*32 + fg*8];
    av[1] = *(const bf16x8*)&Ps[(wr + 16 + fr)*232 + k*32 + fg*8];
    bv[0] = *(const bf16x8*)&Vt_s[er0*232 + k*32 + kx0];
    bv[1] = *(const bf16x8*)&Vt_s[er1*232 + k*32 + kx1];
    acc[0][0] = mfma16(av[0], bv[0], acc[0][0]);
    acc[0][1] = mfma16(av[0], bv[1], acc[0][1]);
    acc[1][0] = mfma16(av[1], bv[0], acc[1][0]);
    acc[1][1] = mfma16(av[1], bv[1], acc[1][1]);
  }
  #pragma unroll
  for (int m = 0; m < 2; ++m)
    #pragma unroll
    for (int n = 0; n < 2; ++n)
      #pragma unroll
      for (int j = 0; j < 4; ++j) {
        int i = i0 + wr + m*16 + fg*4 + j;
        int e = e0 + wc + n*16 + fr;
        if (i < NT)
          out[((size_t)b*NT + i)*DIMD + e] = acc[m][n][j];
      }
}

extern "C" void kernel_launch(void* const* d_in, const int* in_sizes, int n_in,
                              void* d_out, int out_size, void* d_ws, size_t ws_size,
                              hipStream_t stream) {
  const float* x  = (const float*)d_in[0];
  const float* Wq = (const float*)d_in[1];
  const float* Wk = (const float*)d_in[2];
  const float* Wv = (const float*)d_in[3];
  char* ws = (char*)d_ws;
  char* ob = (char*)d_out;

  u16*   wb   = (u16*)(ws + WS_WB);     // [1536][768] bf16: Mt | Wv
  u16*   yv   = (u16*)(ws + WS_YV);     // [52480][1536] bf16 (Y | V), live until k_pv done

  float* S    = (float*)ob;             // [256][205][205] final attn probs (written once by k_sms)
  float* outp = (float*)(ob + DO_OUT);  // [256][205][768] final output (k_pv, last writer)
  u16*   xb   = (u16*)(ob + DO_XB);     // bf16 x (live until k_sms done)
  float* Mt   = (float*)(ob + DO_M);    // [768][768] fp32 Wk^T*Wq = M^T
  float* zz   = (float*)(ob + DO_Z);    // [2048][768] fp32 Xc*M
  float* reg  = (float*)(ob + DO_REG);  // [2048][196] fp32 raw region scores
  float* regm = (float*)(ob + DO_REGM); // [2048][196] fp32 masked region values

  // 1) cast x; exact Mt = Wk^T*Wq (fp32)
  k_cast<<<19680, 256, 0, stream>>>(x, xb, 5038080);
  k_gemm32<1, false><<<144, 256, 0, stream>>>(Wk, Wq, Mt, 768, 768, 768, 768, 12);
  // 2) weight buffer: rows 0-767 = bf16(Mt), rows 768-1535 = bf16(Wv)
  k_cast<<<288, 256, 0, stream>>>(Mt, wb,          73728);
  k_cast<<<288, 256, 0, stream>>>(Wv, wb + 589824, 73728);
  // 3) fused Y|V GEMM (bf16 MFMA): Y = X*M, V = X*Wv^T
  k_yv<<<4920, 256, 0, stream>>>(xb, wb, yv);
  // 4) exact fp32 argmax path: zz = Xc*M (via Mt rows), reg = zz*Xp^T, regm = mask(reg)
  k_gemm32<2, true><<<384, 256, 0, stream>>>(x, Mt, zz, 768, 768, 768, 768, 12);
  k_region<<<2048, 256, 0, stream>>>(zz, x, reg);
  k_maskreg<<<2048, 64, 0, stream>>>(reg, regm);
  // 5) fused scores+mask+softmax -> final attn probs (S written once)
  k_sms<<<1024, 256, 0, stream>>>(yv, xb, regm, S);
  // 6) PV -> final out region
  k_pv<<<12288, 256, 0, stream>>>(S, yv, outp);
}